// Round 17
// baseline (366.495 us; speedup 1.0000x reference)
//
#include <hip/hip_runtime.h>
#include <math.h>

#define LSEQ 16384
#define DM 192
#define DI 384
#define DSN 16
#define DCONV 4
#define DTRK 12
#define NPROJ 44   /* DTRK + 2*DSN */
#define EPSV 1e-5f
#define TCH 32
#define NCH (LSEQ / TCH)          /* 512 chunks */
#define GDIM (DI * DSN)           /* 6144 sequences */
#define RGRP 8                    /* chunks per group */
#define NGRP (NCH / RGRP)         /* 64 groups */
#define CT 8                      /* conv rows per thread */

// z-slice convention for all z=4 kernels: z = dir*2 + order  =>  blk = z,
// order = z&1, sgn = 1-2*(z>>1).

typedef __attribute__((ext_vector_type(8))) short bf16x8;
typedef __attribute__((ext_vector_type(4))) float f32x4;

__device__ __forceinline__ float siluf(float x) { return x / (1.f + __expf(-x)); }
__device__ __forceinline__ float softplus_f(float x) {
  float e = __expf(x);
  float l = __logf(1.f + e);
  return (x > 20.f) ? x : l;
}
__device__ __forceinline__ ushort f2b(float f) {
  uint u = __float_as_uint(f);
  u += 0x7fff + ((u >> 16) & 1);
  return (ushort)(u >> 16);
}
__device__ __forceinline__ float b2f(ushort h) { return __uint_as_float(((uint)h) << 16); }

// a[n] = q^(n+1), log-depth
__device__ __forceinline__ void pow16(float q, float (&a)[16]) {
  float q2 = q*q, q4 = q2*q2, q8 = q4*q4;
  a[0]=q;        a[1]=q2;       a[2]=q2*q;      a[3]=q4;
  a[4]=q4*q;     a[5]=q4*q2;    a[6]=q4*q2*q;   a[7]=q8;
  a[8]=q8*q;     a[9]=q8*q2;    a[10]=q8*q2*q;  a[11]=q8*q4;
  a[12]=q8*q4*q; a[13]=q8*q4*q2;a[14]=q8*q4*q2*q;a[15]=q8*q8;
}

// ---------------- unified weight prep (all 4 blocks) ----------------
#define PREP_A (4 * 768 * DM)
#define PREP_B (4 * 64 * DI)
#define PREP_C (4 * DM * DI)
__global__ void k_prep(const float* __restrict__ Wi, const float* __restrict__ nw,
                       const float* __restrict__ Wx, const float* __restrict__ Wo,
                       ushort* __restrict__ Wct, ushort* __restrict__ Wxt,
                       ushort* __restrict__ Wot) {
  int i = blockIdx.x * 256 + threadIdx.x;
  if (i < PREP_A) {
    int blk = i / (768 * DM), j = i % (768 * DM);
    int n = j / DM, k = j % DM;
    Wct[i] = f2b(nw[blk*DM + k] * Wi[(size_t)blk*DM*768 + (size_t)k*768 + n]);
  } else if (i < PREP_A + PREP_B) {
    int q = i - PREP_A;
    int blk = q / (64 * DI), j = q % (64 * DI);
    int n = j / DI, k = j % DI;
    Wxt[q] = (n < NPROJ) ? f2b(Wx[(size_t)blk*DI*NPROJ + (size_t)k*NPROJ + n]) : (ushort)0;
  } else if (i < PREP_A + PREP_B + PREP_C) {
    int q = i - PREP_A - PREP_B;
    int blk = q / (DM * DI), j = q % (DM * DI);
    int n = j / DI, k = j % DI;
    Wot[q] = f2b(Wo[(size_t)blk*DI*DM + (size_t)k*DM + n]);
  }
}

// ---------------- gather + rmsnorm -> bf16 (both orders, y = order) ----------------
__global__ __launch_bounds__(64) void k_gather_rms(const float* __restrict__ x,
                                                   const int* __restrict__ orders,
                                                   ushort* __restrict__ xon) {
  int t = blockIdx.x;
  int o = blockIdx.y;
  int lane = threadIdx.x;
  int r = orders[(size_t)o*LSEQ + t];
  ushort* xo = xon + (size_t)o*LSEQ*DM;
  float v0 = x[(size_t)r*DM + lane];
  float v1 = x[(size_t)r*DM + 64 + lane];
  float v2 = x[(size_t)r*DM + 128 + lane];
  float ss = v0*v0 + v1*v1 + v2*v2;
  #pragma unroll
  for (int oo = 32; oo > 0; oo >>= 1) ss += __shfl_xor(ss, oo);
  float s = rsqrtf(ss * (1.f/DM) + EPSV);
  xo[(size_t)t*DM + lane]       = f2b(v0 * s);
  xo[(size_t)t*DM + 64 + lane]  = f2b(v1 * s);
  xo[(size_t)t*DM + 128 + lane] = f2b(v2 * s);
}

// ---------------- MFMA GEMM, z-batched (z up to 4). x = M-tile, y = N-tile ----------------
// AMODE 0: A bf16 (lda), A += (z&aMask)*sA. AMODE 1: A[m][k] = b2f(Y)*silu(b2f(Z)).
// OMODE 0: f32 out. OMODE 1: bf16 out. OMODE 2: bf16 split at col 384 (C0/C1, ld 384).
template<int MI, int AMODE, int OMODE>
__global__ __launch_bounds__(256) void k_mm(
    const ushort* __restrict__ A, const ushort* __restrict__ Yp,
    const ushort* __restrict__ Zp, const ushort* __restrict__ Bt,
    void* __restrict__ C0, void* __restrict__ C1,
    int N, int K, int lda, int ldz, int ldc, int aMask,
    long sA, long sY, long sZ, long sB, long sC)
{
  __shared__ __align__(16) ushort As[32 * MI * 64];
  __shared__ __align__(16) ushort Bs[64 * 64];
  const int z = blockIdx.z;
  if (AMODE == 0) A += (size_t)(z & aMask) * sA;
  else { Yp += (size_t)z * sY; Zp += (size_t)z * sZ; }
  Bt += (size_t)z * sB;
  const int bm = blockIdx.x * (32 * MI), bn = blockIdx.y * 64;
  const int tid = threadIdx.x;
  const int l = tid & 63, w = tid >> 6;
  const int wm = w & 1, wn = w >> 1;
  f32x4 acc[MI][2] = {};

  for (int k0 = 0; k0 < K; k0 += 64) {
    #pragma unroll
    for (int p = 0; p < MI; p++) {
      int c = tid + p * 256;
      int row = c >> 3, ko = (c & 7) * 8;
      int sw = (row * 128 + (c & 7) * 16) ^ ((row & 7) << 4);
      if (AMODE == 0) {
        uint4 v = *(const uint4*)(A + (size_t)(bm + row) * lda + k0 + ko);
        *(uint4*)((char*)As + sw) = v;
      } else {
        const ushort* yrow = Yp + (size_t)(bm + row) * lda + k0 + ko;
        const ushort* zrow = Zp + (size_t)(bm + row) * ldz + k0 + ko;
        ushort tmp[8];
        #pragma unroll
        for (int j = 0; j < 8; j++) {
          float zz = b2f(zrow[j]);
          tmp[j] = f2b(b2f(yrow[j]) * (zz / (1.f + __expf(-zz))));
        }
        *(uint4*)((char*)As + sw) = *(const uint4*)tmp;
      }
    }
    #pragma unroll
    for (int p = 0; p < 2; p++) {
      int c = tid + p * 256;
      int row = c >> 3, ko = (c & 7) * 8;
      int sw = (row * 128 + (c & 7) * 16) ^ ((row & 7) << 4);
      uint4 v = *(const uint4*)(Bt + (size_t)(bn + row) * K + k0 + ko);
      *(uint4*)((char*)Bs + sw) = v;
    }
    __syncthreads();
    #pragma unroll
    for (int ks = 0; ks < 2; ks++) {
      bf16x8 af[MI], bfv[2];
      #pragma unroll
      for (int mi = 0; mi < MI; mi++) {
        int r = 16 * MI * wm + 16 * mi + (l & 15);
        int ad = (r * 128 + 32 * ks + 16 * (l >> 4)) ^ ((r & 7) << 4);
        af[mi] = *(const bf16x8*)((const char*)As + ad);
      }
      #pragma unroll
      for (int ni = 0; ni < 2; ni++) {
        int r = 32 * wn + 16 * ni + (l & 15);
        int ad = (r * 128 + 32 * ks + 16 * (l >> 4)) ^ ((r & 7) << 4);
        bfv[ni] = *(const bf16x8*)((const char*)Bs + ad);
      }
      #pragma unroll
      for (int mi = 0; mi < MI; mi++)
        #pragma unroll
        for (int ni = 0; ni < 2; ni++)
          acc[mi][ni] = __builtin_amdgcn_mfma_f32_16x16x32_bf16(
              af[mi], bfv[ni], acc[mi][ni], 0, 0, 0);
    }
    __syncthreads();
  }

  #pragma unroll
  for (int mi = 0; mi < MI; mi++) {
    #pragma unroll
    for (int ni = 0; ni < 2; ni++) {
      int c0 = bn + 32 * wn + 16 * ni + (l & 15);
      if (OMODE != 2 && c0 >= N) continue;
      int r0 = bm + 16 * MI * wm + 16 * mi + 4 * (l >> 4);
      #pragma unroll
      for (int j = 0; j < 4; j++) {
        if (OMODE == 0) {
          ((float*)C0 + (size_t)z*sC)[(size_t)(r0 + j) * ldc + c0] = acc[mi][ni][j];
        } else if (OMODE == 1) {
          ((ushort*)C0 + (size_t)z*sC)[(size_t)(r0 + j) * ldc + c0] = f2b(acc[mi][ni][j]);
        } else {
          if (c0 < 384)
            ((ushort*)C0 + (size_t)z*sC)[(size_t)(r0 + j) * 384 + c0] = f2b(acc[mi][ni][j]);
          else
            ((ushort*)C1 + (size_t)z*sC)[(size_t)(r0 + j) * 384 + (c0 - 384)] = f2b(acc[mi][ni][j]);
        }
      }
    }
  }
}

// ---------------- causal depthwise conv + silu: rolling window, CT rows/thread, z=4 ----------------
__global__ __launch_bounds__(256) void k_conv(const ushort* __restrict__ XC,
                                              const float* __restrict__ cw,
                                              const float* __restrict__ cb,
                                              ushort* __restrict__ U) {
  int z = blockIdx.y;
  int blk = z;
  int sgn = 1 - 2*(z >> 1);
  int i = blockIdx.x * 256 + threadIdx.x;     // over (LSEQ/CT)*(DI/8)
  if (i >= (LSEQ/CT) * (DI/8)) return;
  int tb = i / (DI/8), d0 = (i % (DI/8)) * 8;
  const ushort* X = XC + (size_t)z*LSEQ*DI;
  ushort* Uz = U + (size_t)z*LSEQ*DI;

  float wv[4][8];
  #pragma unroll
  for (int j = 0; j < 8; j++) {
    float4 t4 = *(const float4*)(cw + (size_t)blk*DI*DCONV + (d0+j)*DCONV);
    wv[0][j]=t4.x; wv[1][j]=t4.y; wv[2][j]=t4.z; wv[3][j]=t4.w;
  }
  float cbv[8];
  *(float4*)&cbv[0] = *(const float4*)(cb + blk*DI + d0);
  *(float4*)&cbv[4] = *(const float4*)(cb + blk*DI + d0 + 4);

  int tau0 = tb * CT;
  float win[3][8];
  #pragma unroll
  for (int q = 0; q < 3; q++) {
    int tau = tau0 - 3 + q;
    if (tau >= 0) {
      int r = (sgn > 0) ? tau : (LSEQ-1-tau);
      uint4 xv = *(const uint4*)(X + (size_t)r*DI + d0);
      const ushort* xs = (const ushort*)&xv;
      #pragma unroll
      for (int j = 0; j < 8; j++) win[q][j] = b2f(xs[j]);
    } else {
      #pragma unroll
      for (int j = 0; j < 8; j++) win[q][j] = 0.f;
    }
  }
  #pragma unroll
  for (int tt = 0; tt < CT; tt++) {
    int tau = tau0 + tt;
    int r = (sgn > 0) ? tau : (LSEQ-1-tau);
    float cur[8];
    uint4 xv = *(const uint4*)(X + (size_t)r*DI + d0);
    const ushort* xs = (const ushort*)&xv;
    #pragma unroll
    for (int j = 0; j < 8; j++) cur[j] = b2f(xs[j]);
    ushort outv[8];
    #pragma unroll
    for (int j = 0; j < 8; j++) {
      float a = cbv[j];
      a = fmaf(wv[0][j], win[0][j], a);
      a = fmaf(wv[1][j], win[1][j], a);
      a = fmaf(wv[2][j], win[2][j], a);
      a = fmaf(wv[3][j], cur[j],    a);
      outv[j] = f2b(siluf(a));
    }
    *(uint4*)(Uz + (size_t)r*DI + d0) = *(const uint4*)outv;
    #pragma unroll
    for (int j = 0; j < 8; j++) {
      win[0][j] = win[1][j]; win[1][j] = win[2][j]; win[2][j] = cur[j];
    }
  }
}

// ---------------- scan phase 1 (z=4, 384-thr blocks, d = tid): LDS Ps staged once ----------------
__global__ __launch_bounds__(384) void k_scan1(const ushort* __restrict__ UC,
                                               const float* __restrict__ PROJ,
                                               const float* __restrict__ Alog,
                                               const float* __restrict__ Wdt,
                                               const float* __restrict__ bdt,
                                               const float* __restrict__ Dp,
                                               float* __restrict__ Dc,
                                               ushort* __restrict__ Sc,
                                               ushort* __restrict__ Y) {
  __shared__ float Ps[TCH][NPROJ];
  int z = blockIdx.y;
  int blk = z;
  int sgn = 1 - 2*(z >> 1);
  const ushort* Uz = UC + (size_t)z*LSEQ*DI;
  const float* Pz = PROJ + (size_t)z*LSEQ*NPROJ;
  ushort* Yz = Y + (size_t)z*LSEQ*DI;
  int c = blockIdx.x;
  int tid = threadIdx.x;
  int d = tid;
  if (tid < TCH * 11) {
    int row = tid / 11, q4 = tid % 11;
    int s = c*TCH + row;
    int rg = (sgn > 0) ? s : (LSEQ-1-s);
    *(float4*)&Ps[row][q4*4] = *(const float4*)(Pz + (size_t)rg*NPROJ + q4*4);
  }
  __syncthreads();

  float wdt[DTRK];
  #pragma unroll
  for (int k = 0; k < DTRK; k++) wdt[k] = Wdt[(size_t)blk*DTRK*DI + k*DI + d];
  float bdtv = bdt[blk*DI + d];
  const float* Ablk = Alog + (size_t)blk*GDIM + (size_t)d*DSN;
  bool fast = true;
  #pragma unroll
  for (int n = 0; n < DSN; n++) {
    float An = -__expf(Ablk[n]);
    fast = fast && (fabsf(An + (float)(n+1)) <= 1e-3f * (n+1));
  }
  float dskip = Dp[blk*DI + d];
  float S[DSN] = {};
  float dtsum = 0.f;
  for (int t = 0; t < TCH; t++) {
    int s = c*TCH + t;
    int row = (sgn > 0) ? s : (LSEQ-1-s);
    float u = b2f(Uz[(size_t)row*DI + d]);
    const float* pr = &Ps[t][0];
    float dtp[12], Bv[DSN], Cv[DSN];
    *(float4*)&dtp[0] = *(const float4*)(pr + 0);
    *(float4*)&dtp[4] = *(const float4*)(pr + 4);
    *(float4*)&dtp[8] = *(const float4*)(pr + 8);
    *(float4*)&Bv[0]  = *(const float4*)(pr + 12);
    *(float4*)&Bv[4]  = *(const float4*)(pr + 16);
    *(float4*)&Bv[8]  = *(const float4*)(pr + 20);
    *(float4*)&Bv[12] = *(const float4*)(pr + 24);
    *(float4*)&Cv[0]  = *(const float4*)(pr + 28);
    *(float4*)&Cv[4]  = *(const float4*)(pr + 32);
    *(float4*)&Cv[8]  = *(const float4*)(pr + 36);
    *(float4*)&Cv[12] = *(const float4*)(pr + 40);
    float xdt = bdtv;
    #pragma unroll
    for (int k = 0; k < DTRK; k++) xdt = fmaf(dtp[k], wdt[k], xdt);
    float dtv = softplus_f(xdt);
    float du = dtv * u;
    dtsum += dtv;
    float a[DSN];
    if (fast) { pow16(__expf(-dtv), a); }
    else {
      #pragma unroll
      for (int n = 0; n < DSN; n++) a[n] = __expf(dtv * -__expf(Ablk[n]));
    }
    float y = u * dskip;
    #pragma unroll
    for (int n = 0; n < DSN; n++) {
      S[n] = a[n] * S[n] + du * Bv[n];
      y += S[n] * Cv[n];
    }
    Yz[(size_t)row * DI + d] = f2b(y);
  }
  Dc[(size_t)z*NCH*DI + (size_t)c*DI + d] = dtsum;
  ushort st[16];
  #pragma unroll
  for (int n = 0; n < DSN; n++) st[n] = f2b(S[n]);
  ushort* sp = Sc + (size_t)z*NCH*GDIM + (size_t)c*GDIM + (size_t)d*DSN;
  *(uint4*)sp       = *(const uint4*)&st[0];
  *(uint4*)(sp + 8) = *(const uint4*)&st[8];
}

// ---------------- scan 2a: compose 8-chunk groups (p regenerated from Dc), z=4 ----------------
__global__ __launch_bounds__(256) void k_scan2a(const float* __restrict__ Dc,
                                                const ushort* __restrict__ Sc,
                                                const float* __restrict__ Alog,
                                                float* __restrict__ PL,
                                                float* __restrict__ SL) {
  int g = blockIdx.x * 256 + threadIdx.x;
  int l = blockIdx.y;
  int z = blockIdx.z;
  int blk = z;
  int d = g >> 4;
  float A = -__expf(Alog[(size_t)blk*GDIM + g]);
  const float* Dz = Dc + (size_t)z*NCH*DI;
  const ushort* Sz = Sc + (size_t)z*NCH*GDIM;
  float Da = 0.f, Sa = 0.f;
  #pragma unroll
  for (int j = 0; j < RGRP; j++) {
    int c = l*RGRP + j;
    float D = Dz[(size_t)c*DI + d];
    float p = __expf(A * D);
    Sa = fmaf(p, Sa, b2f(Sz[(size_t)c*GDIM + g]));
    Da += D;
  }
  PL[(size_t)z*NGRP*GDIM + (size_t)l * GDIM + g] = __expf(A * Da);
  SL[(size_t)z*NGRP*GDIM + (size_t)l * GDIM + g] = Sa;
}

// ---------------- scan 2b: serial scan over 64 group summaries, z=4 ----------------
__global__ __launch_bounds__(256) void k_scan2b(const float* __restrict__ PL,
                                                const float* __restrict__ SL,
                                                float* __restrict__ HL) {
  int g = blockIdx.x * 256 + threadIdx.x;
  int z = blockIdx.y;
  const float* Pz = PL + (size_t)z*NGRP*GDIM;
  const float* Sz = SL + (size_t)z*NGRP*GDIM;
  float* Hz = HL + (size_t)z*NGRP*GDIM;
  float p[NGRP], s[NGRP];
  #pragma unroll
  for (int l = 0; l < NGRP; l++) {
    p[l] = Pz[(size_t)l * GDIM + g];
    s[l] = Sz[(size_t)l * GDIM + g];
  }
  float H = 0.f;
  #pragma unroll
  for (int l = 0; l < NGRP; l++) {
    Hz[(size_t)l * GDIM + g] = H;
    H = fmaf(p[l], H, s[l]);
  }
}

// ---------------- scan 2c: expand group states to per-chunk init states (Hc bf16), z=4 ----------------
__global__ __launch_bounds__(256) void k_scan2c(const float* __restrict__ Dc,
                                                const ushort* __restrict__ Sc,
                                                const float* __restrict__ HL,
                                                const float* __restrict__ Alog,
                                                ushort* __restrict__ Hc) {
  int g = blockIdx.x * 256 + threadIdx.x;
  int l = blockIdx.y;
  int z = blockIdx.z;
  int blk = z;
  int d = g >> 4;
  float A = -__expf(Alog[(size_t)blk*GDIM + g]);
  const float* Dz = Dc + (size_t)z*NCH*DI;
  const ushort* Sz = Sc + (size_t)z*NCH*GDIM;
  float h = HL[(size_t)z*NGRP*GDIM + (size_t)l * GDIM + g];
  ushort* Hz = Hc + (size_t)z*NCH*GDIM;
  #pragma unroll
  for (int j = 0; j < RGRP; j++) {
    int c = l*RGRP + j;
    size_t off = (size_t)c * GDIM + g;
    Hz[off] = f2b(h);
    float p = __expf(A * Dz[(size_t)c*DI + d]);
    h = fmaf(p, h, b2f(Sz[off]));
  }
}

// ---------------- fix (z=4, 384-thr blocks, d = tid): dt recomputed; staged once ----------------
__global__ __launch_bounds__(384) void k_fix(const ushort* __restrict__ Hc,
                                             const float* __restrict__ PROJ,
                                             const float* __restrict__ Alog,
                                             const float* __restrict__ Wdt,
                                             const float* __restrict__ bdt,
                                             ushort* __restrict__ Y) {
  __shared__ float Dts[TCH][DTRK];
  __shared__ float Cs[TCH][DSN];
  int z = blockIdx.y;
  int c = blockIdx.x;
  int blk = z;
  int sgn = 1 - 2*(z >> 1);
  int tid = threadIdx.x;
  int d = tid;
  const float* Pz = PROJ + (size_t)z*LSEQ*NPROJ;
  ushort* Yz = Y + (size_t)z*LSEQ*DI;

  // stage dt cols (0..11) and C cols (28..43) for this chunk, once
  if (tid < TCH * 3) {
    int row = tid / 3, q4 = tid % 3;
    int s = c*TCH + row;
    int rg = (sgn > 0) ? s : (LSEQ-1-s);
    *(float4*)&Dts[row][q4*4] = *(const float4*)(Pz + (size_t)rg*NPROJ + q4*4);
  } else if (tid < TCH * 3 + TCH * 4) {
    int q = tid - TCH * 3;
    int row = q >> 2, q4 = q & 3;
    int s = c*TCH + row;
    int rg = (sgn > 0) ? s : (LSEQ-1-s);
    *(float4*)&Cs[row][q4*4] = *(const float4*)(Pz + (size_t)rg*NPROJ + 28 + q4*4);
  }

  float wdt[DTRK];
  #pragma unroll
  for (int k = 0; k < DTRK; k++) wdt[k] = Wdt[(size_t)blk*DTRK*DI + k*DI + d];
  float bdtv = bdt[blk*DI + d];
  const float* Ablk = Alog + (size_t)blk*GDIM + (size_t)d*DSN;
  bool fast = true;
  #pragma unroll
  for (int n = 0; n < DSN; n++) {
    float An = -__expf(Ablk[n]);
    fast = fast && (fabsf(An + (float)(n+1)) <= 1e-3f * (n+1));
  }
  float h[DSN];
  {
    const ushort* hp = Hc + (size_t)z*NCH*GDIM + (size_t)c*GDIM + (size_t)d*DSN;
    uint4 h0 = *(const uint4*)hp;
    uint4 h1 = *(const uint4*)(hp + 8);
    const ushort* hs0 = (const ushort*)&h0;
    const ushort* hs1 = (const ushort*)&h1;
    #pragma unroll
    for (int n = 0; n < 8; n++) { h[n] = b2f(hs0[n]); h[8+n] = b2f(hs1[n]); }
  }
  __syncthreads();

  float cd = 0.f;
  for (int t = 0; t < TCH; t++) {
    int s = c*TCH + t;
    int row = (sgn > 0) ? s : (LSEQ-1-s);
    float dtp[12], Cv[DSN];
    *(float4*)&dtp[0] = *(const float4*)&Dts[t][0];
    *(float4*)&dtp[4] = *(const float4*)&Dts[t][4];
    *(float4*)&dtp[8] = *(const float4*)&Dts[t][8];
    *(float4*)&Cv[0]  = *(const float4*)&Cs[t][0];
    *(float4*)&Cv[4]  = *(const float4*)&Cs[t][4];
    *(float4*)&Cv[8]  = *(const float4*)&Cs[t][8];
    *(float4*)&Cv[12] = *(const float4*)&Cs[t][12];
    float xdt = bdtv;
    #pragma unroll
    for (int k = 0; k < DTRK; k++) xdt = fmaf(dtp[k], wdt[k], xdt);
    cd += softplus_f(xdt);
    float p[DSN];
    if (fast) { pow16(__expf(-cd), p); }
    else {
      #pragma unroll
      for (int n = 0; n < DSN; n++) p[n] = __expf(cd * -__expf(Ablk[n]));
    }
    float corr = 0.f;
    #pragma unroll
    for (int n = 0; n < DSN; n++)
      corr = fmaf(p[n] * h[n], Cv[n], corr);
    size_t yi = (size_t)row*DI + d;
    Yz[yi] = f2b(b2f(Yz[yi]) + corr);
  }
}

// ---------------- final combine ----------------
__device__ __forceinline__ void ln_row(float (&v)[3], const float* __restrict__ w,
                                       const float* __restrict__ b, int lane) {
  float s = v[0] + v[1] + v[2];
  #pragma unroll
  for (int o = 32; o > 0; o >>= 1) s += __shfl_xor(s, o);
  float m = s * (1.f / DM);
  float q = 0.f;
  #pragma unroll
  for (int i = 0; i < 3; i++) { float d = v[i] - m; q += d*d; }
  #pragma unroll
  for (int o = 32; o > 0; o >>= 1) q += __shfl_xor(q, o);
  float inv = rsqrtf(q * (1.f / DM) + EPSV);
  #pragma unroll
  for (int i = 0; i < 3; i++) v[i] = (v[i] - m) * inv * w[lane + 64*i] + b[lane + 64*i];
}

// FIRST=1: out = x + cb (idx is a permutation). FIRST=0: out += cb.
template<int FIRST>
__global__ __launch_bounds__(64) void k_final(const float* __restrict__ x,
                                              const int* __restrict__ idx,
                                              const ushort* __restrict__ G4f,
                                              const ushort* __restrict__ G4b,
                                              const float* __restrict__ lnfw,
                                              const float* __restrict__ lnfb,
                                              const float* __restrict__ lnbw,
                                              const float* __restrict__ lnbb,
                                              const float* __restrict__ lnow,
                                              const float* __restrict__ lnob,
                                              float* __restrict__ out) {
  int t = blockIdx.x, lane = threadIdx.x;
  int r = idx[t];
  float f[3], g[3], cb[3];
  #pragma unroll
  for (int i = 0; i < 3; i++) {
    int j = lane + 64*i;
    float xo = x[(size_t)r*DM + j];
    f[i] = xo + b2f(G4f[(size_t)t*DM + j]);
    g[i] = xo + b2f(G4b[(size_t)t*DM + j]);
  }
  ln_row(f, lnfw, lnfb, lane);
  ln_row(g, lnbw, lnbb, lane);
  #pragma unroll
  for (int i = 0; i < 3; i++) cb[i] = f[i] + g[i];
  ln_row(cb, lnow, lnob, lane);
  #pragma unroll
  for (int i = 0; i < 3; i++) {
    int j = lane + 64*i;
    if (FIRST)
      out[(size_t)r*DM + j] = x[(size_t)r*DM + j] + cb[i];
    else
      out[(size_t)r*DM + j] += cb[i];
  }
}

extern "C" void kernel_launch(void* const* d_in, const int* in_sizes, int n_in,
                              void* d_out, int out_size, void* d_ws, size_t ws_size,
                              hipStream_t stream) {
  const float* x      = (const float*)d_in[0];
  const int*   orders = (const int*)  d_in[1];
  const float* nw     = (const float*)d_in[2];
  const float* Wi     = (const float*)d_in[3];
  const float* cw     = (const float*)d_in[4];
  const float* cbi    = (const float*)d_in[5];
  const float* Wx     = (const float*)d_in[6];
  const float* Wdt    = (const float*)d_in[7];
  const float* bdt    = (const float*)d_in[8];
  const float* Alog   = (const float*)d_in[9];
  const float* Dp     = (const float*)d_in[10];
  const float* Wo     = (const float*)d_in[11];
  const float* flw    = (const float*)d_in[12];
  const float* flb    = (const float*)d_in[13];
  const float* blw    = (const float*)d_in[14];
  const float* blb    = (const float*)d_in[15];
  const float* olw    = (const float*)d_in[16];
  const float* olb    = (const float*)d_in[17];
  float* outp = (float*)d_out;

  char* w = (char*)d_ws;
  size_t off = 0;
  auto take = [&](size_t bytes) -> void* {
    char* p = w + off;
    off += (bytes + 255) & ~(size_t)255;
    return (void*)p;
  };
  // z-slices: z = dir*2 + order, blk = z.
  ushort* Wct  = (ushort*)take((size_t)4 * 768 * DM * 2);
  ushort* Wxt  = (ushort*)take((size_t)4 * 64 * DI * 2);
  ushort* Wot  = (ushort*)take((size_t)4 * DM * DI * 2);
  ushort* xon  = (ushort*)take((size_t)2 * LSEQ * DM * 2);    // per order
  ushort* xc   = (ushort*)take((size_t)4 * LSEQ * DI * 2);    // per z; later aliased by ybuf
  ushort* zc   = (ushort*)take((size_t)4 * LSEQ * DI * 2);
  ushort* uc   = (ushort*)take((size_t)4 * LSEQ * DI * 2);    // conv out; later aliased by Hc
  float*  proj = (float*) take((size_t)4 * LSEQ * NPROJ * 4);
  ushort* g4   = (ushort*)take((size_t)4 * LSEQ * DM * 2);
  float*  Dc   = (float*) take((size_t)4 * NCH * DI * 4);
  ushort* Sc   = (ushort*)take((size_t)4 * NCH * GDIM * 2);
  float*  PL   = (float*) take((size_t)4 * NGRP * GDIM * 4);
  float*  SL   = (float*) take((size_t)4 * NGRP * GDIM * 4);
  float*  HL   = (float*) take((size_t)4 * NGRP * GDIM * 4);
  ushort* ybuf = xc;   // xc dead after conv; scan1 writes yhat here
  ushort* Hc   = uc;   // uc dead after scan1; 2c writes chunk-init states here
  (void)ws_size; (void)n_in; (void)in_sizes; (void)out_size;

  // weight prep, all 4 blocks, once
  k_prep<<<(PREP_A + PREP_B + PREP_C + 255)/256, 256, 0, stream>>>(
      Wi, nw, Wx, Wo, Wct, Wxt, Wot);
  // gather+rms for both orders
  k_gather_rms<<<dim3(LSEQ, 2), 64, 0, stream>>>(x, orders, xon);

  // in-proj (z=4): xc/zc = xon[z&1] @ Wc[z]
  k_mm<4,0,2><<<dim3(LSEQ/128, 768/64, 4), 256, 0, stream>>>(
      xon, nullptr, nullptr, Wct, xc, zc, 768, DM, DM, 0, 384, 1,
      (long)LSEQ*DM, 0L, 0L, (long)768*DM, (long)LSEQ*DI);
  // conv (z=4): uc = silu(conv(xc))
  k_conv<<<dim3(((LSEQ/CT)*(DI/8) + 255)/256, 4), 256, 0, stream>>>(
      xc, cw, cbi, uc);
  // x-proj (z=4): proj = uc @ Wx
  k_mm<2,0,0><<<dim3(LSEQ/64, 1, 4), 256, 0, stream>>>(
      uc, nullptr, nullptr, Wxt, proj, nullptr, NPROJ, DI, DI, 0, NPROJ, 3,
      (long)LSEQ*DI, 0L, 0L, (long)64*DI, (long)LSEQ*NPROJ);
  // scan1 (z=4, 384-thr): local scan + yhat + chunk D/S
  k_scan1<<<dim3(NCH, 4), 384, 0, stream>>>(
      uc, proj, Alog, Wdt, bdt, Dp, Dc, Sc, ybuf);
  k_scan2a<<<dim3(GDIM/256, NGRP, 4), 256, 0, stream>>>(Dc, Sc, Alog, PL, SL);
  k_scan2b<<<dim3(GDIM/256, 4), 256, 0, stream>>>(PL, SL, HL);
  k_scan2c<<<dim3(GDIM/256, NGRP, 4), 256, 0, stream>>>(Dc, Sc, HL, Alog, Hc);
  // fix (z=4, 384-thr): in-place correction of ybuf (dt recomputed)
  k_fix<<<dim3(NCH, 4), 384, 0, stream>>>(
      Hc, proj, Alog, Wdt, bdt, ybuf);
  // out-proj (z=4): g4 = (y * silu(z)) @ Wo
  k_mm<2,1,1><<<dim3(LSEQ/64, DM/64, 4), 256, 0, stream>>>(
      nullptr, ybuf, zc, Wot, g4, nullptr, DM, DI, DI, DI, DM, 3,
      0L, (long)LSEQ*DI, (long)LSEQ*DI, (long)DM*DI, (long)LSEQ*DM);

  // final: order 0 (z slices 0 fwd, 2 bwd) then order 1 (1 fwd, 3 bwd)
  k_final<1><<<LSEQ, 64, 0, stream>>>(x, orders, g4, g4 + (size_t)2*LSEQ*DM,
      flw, flb, blw, blb, olw, olb, outp);
  k_final<0><<<LSEQ, 64, 0, stream>>>(x, orders + LSEQ,
      g4 + (size_t)1*LSEQ*DM, g4 + (size_t)3*LSEQ*DM,
      flw + DM, flb + DM, blw + DM, blb + DM, olw + DM, olb + DM, outp);
}

// Round 18
// 333.142 us; speedup vs baseline: 1.1001x; 1.1001x over previous
//
#include <hip/hip_runtime.h>
#include <math.h>

#define LSEQ 16384
#define DM 192
#define DI 384
#define DSN 16
#define DCONV 4
#define DTRK 12
#define NPROJ 44   /* DTRK + 2*DSN */
#define EPSV 1e-5f
#define TCH 32
#define NCH (LSEQ / TCH)          /* 512 chunks */
#define GDIM (DI * DSN)           /* 6144 sequences */
#define RGRP 8                    /* chunks per group */
#define NGRP (NCH / RGRP)         /* 64 groups */
#define CT 8                      /* conv rows per thread */

// z-slice convention for all z=4 kernels: z = dir*2 + order  =>  blk = z,
// order = z&1, sgn = 1-2*(z>>1).

typedef __attribute__((ext_vector_type(8))) short bf16x8;
typedef __attribute__((ext_vector_type(4))) float f32x4;

__device__ __forceinline__ float siluf(float x) { return x / (1.f + __expf(-x)); }
__device__ __forceinline__ float softplus_f(float x) {
  float e = __expf(x);
  float l = __logf(1.f + e);
  return (x > 20.f) ? x : l;
}
__device__ __forceinline__ ushort f2b(float f) {
  uint u = __float_as_uint(f);
  u += 0x7fff + ((u >> 16) & 1);
  return (ushort)(u >> 16);
}
__device__ __forceinline__ float b2f(ushort h) { return __uint_as_float(((uint)h) << 16); }

// a[n] = q^(n+1), log-depth
__device__ __forceinline__ void pow16(float q, float (&a)[16]) {
  float q2 = q*q, q4 = q2*q2, q8 = q4*q4;
  a[0]=q;        a[1]=q2;       a[2]=q2*q;      a[3]=q4;
  a[4]=q4*q;     a[5]=q4*q2;    a[6]=q4*q2*q;   a[7]=q8;
  a[8]=q8*q;     a[9]=q8*q2;    a[10]=q8*q2*q;  a[11]=q8*q4;
  a[12]=q8*q4*q; a[13]=q8*q4*q2;a[14]=q8*q4*q2*q;a[15]=q8*q8;
}

// ---------------- unified weight prep (all 4 blocks) ----------------
#define PREP_A (4 * 768 * DM)
#define PREP_B (4 * 64 * DI)
#define PREP_C (4 * DM * DI)
__global__ void k_prep(const float* __restrict__ Wi, const float* __restrict__ nw,
                       const float* __restrict__ Wx, const float* __restrict__ Wo,
                       ushort* __restrict__ Wct, ushort* __restrict__ Wxt,
                       ushort* __restrict__ Wot) {
  int i = blockIdx.x * 256 + threadIdx.x;
  if (i < PREP_A) {
    int blk = i / (768 * DM), j = i % (768 * DM);
    int n = j / DM, k = j % DM;
    Wct[i] = f2b(nw[blk*DM + k] * Wi[(size_t)blk*DM*768 + (size_t)k*768 + n]);
  } else if (i < PREP_A + PREP_B) {
    int q = i - PREP_A;
    int blk = q / (64 * DI), j = q % (64 * DI);
    int n = j / DI, k = j % DI;
    Wxt[q] = (n < NPROJ) ? f2b(Wx[(size_t)blk*DI*NPROJ + (size_t)k*NPROJ + n]) : (ushort)0;
  } else if (i < PREP_A + PREP_B + PREP_C) {
    int q = i - PREP_A - PREP_B;
    int blk = q / (DM * DI), j = q % (DM * DI);
    int n = j / DI, k = j % DI;
    Wot[q] = f2b(Wo[(size_t)blk*DI*DM + (size_t)k*DM + n]);
  }
}

// ---------------- gather + rmsnorm -> bf16 (both orders, y = order) ----------------
__global__ __launch_bounds__(64) void k_gather_rms(const float* __restrict__ x,
                                                   const int* __restrict__ orders,
                                                   ushort* __restrict__ xon) {
  int t = blockIdx.x;
  int o = blockIdx.y;
  int lane = threadIdx.x;
  int r = orders[(size_t)o*LSEQ + t];
  ushort* xo = xon + (size_t)o*LSEQ*DM;
  float v0 = x[(size_t)r*DM + lane];
  float v1 = x[(size_t)r*DM + 64 + lane];
  float v2 = x[(size_t)r*DM + 128 + lane];
  float ss = v0*v0 + v1*v1 + v2*v2;
  #pragma unroll
  for (int oo = 32; oo > 0; oo >>= 1) ss += __shfl_xor(ss, oo);
  float s = rsqrtf(ss * (1.f/DM) + EPSV);
  xo[(size_t)t*DM + lane]       = f2b(v0 * s);
  xo[(size_t)t*DM + 64 + lane]  = f2b(v1 * s);
  xo[(size_t)t*DM + 128 + lane] = f2b(v2 * s);
}

// ---------------- MFMA GEMM, z-batched (z up to 4). x = M-tile, y = N-tile ----------------
// AMODE 0: A bf16 (lda), A += (z&aMask)*sA. AMODE 1: A[m][k] = b2f(Y)*silu(b2f(Z)).
// OMODE 0: f32 out. OMODE 1: bf16 out. OMODE 2: bf16 split at col 384 (C0/C1, ld 384).
template<int MI, int AMODE, int OMODE>
__global__ __launch_bounds__(256) void k_mm(
    const ushort* __restrict__ A, const ushort* __restrict__ Yp,
    const ushort* __restrict__ Zp, const ushort* __restrict__ Bt,
    void* __restrict__ C0, void* __restrict__ C1,
    int N, int K, int lda, int ldz, int ldc, int aMask,
    long sA, long sY, long sZ, long sB, long sC)
{
  __shared__ __align__(16) ushort As[32 * MI * 64];
  __shared__ __align__(16) ushort Bs[64 * 64];
  const int z = blockIdx.z;
  if (AMODE == 0) A += (size_t)(z & aMask) * sA;
  else { Yp += (size_t)z * sY; Zp += (size_t)z * sZ; }
  Bt += (size_t)z * sB;
  const int bm = blockIdx.x * (32 * MI), bn = blockIdx.y * 64;
  const int tid = threadIdx.x;
  const int l = tid & 63, w = tid >> 6;
  const int wm = w & 1, wn = w >> 1;
  f32x4 acc[MI][2] = {};

  for (int k0 = 0; k0 < K; k0 += 64) {
    #pragma unroll
    for (int p = 0; p < MI; p++) {
      int c = tid + p * 256;
      int row = c >> 3, ko = (c & 7) * 8;
      int sw = (row * 128 + (c & 7) * 16) ^ ((row & 7) << 4);
      if (AMODE == 0) {
        uint4 v = *(const uint4*)(A + (size_t)(bm + row) * lda + k0 + ko);
        *(uint4*)((char*)As + sw) = v;
      } else {
        const ushort* yrow = Yp + (size_t)(bm + row) * lda + k0 + ko;
        const ushort* zrow = Zp + (size_t)(bm + row) * ldz + k0 + ko;
        ushort tmp[8];
        #pragma unroll
        for (int j = 0; j < 8; j++) {
          float zz = b2f(zrow[j]);
          tmp[j] = f2b(b2f(yrow[j]) * (zz / (1.f + __expf(-zz))));
        }
        *(uint4*)((char*)As + sw) = *(const uint4*)tmp;
      }
    }
    #pragma unroll
    for (int p = 0; p < 2; p++) {
      int c = tid + p * 256;
      int row = c >> 3, ko = (c & 7) * 8;
      int sw = (row * 128 + (c & 7) * 16) ^ ((row & 7) << 4);
      uint4 v = *(const uint4*)(Bt + (size_t)(bn + row) * K + k0 + ko);
      *(uint4*)((char*)Bs + sw) = v;
    }
    __syncthreads();
    #pragma unroll
    for (int ks = 0; ks < 2; ks++) {
      bf16x8 af[MI], bfv[2];
      #pragma unroll
      for (int mi = 0; mi < MI; mi++) {
        int r = 16 * MI * wm + 16 * mi + (l & 15);
        int ad = (r * 128 + 32 * ks + 16 * (l >> 4)) ^ ((r & 7) << 4);
        af[mi] = *(const bf16x8*)((const char*)As + ad);
      }
      #pragma unroll
      for (int ni = 0; ni < 2; ni++) {
        int r = 32 * wn + 16 * ni + (l & 15);
        int ad = (r * 128 + 32 * ks + 16 * (l >> 4)) ^ ((r & 7) << 4);
        bfv[ni] = *(const bf16x8*)((const char*)Bs + ad);
      }
      #pragma unroll
      for (int mi = 0; mi < MI; mi++)
        #pragma unroll
        for (int ni = 0; ni < 2; ni++)
          acc[mi][ni] = __builtin_amdgcn_mfma_f32_16x16x32_bf16(
              af[mi], bfv[ni], acc[mi][ni], 0, 0, 0);
    }
    __syncthreads();
  }

  #pragma unroll
  for (int mi = 0; mi < MI; mi++) {
    #pragma unroll
    for (int ni = 0; ni < 2; ni++) {
      int c0 = bn + 32 * wn + 16 * ni + (l & 15);
      if (OMODE != 2 && c0 >= N) continue;
      int r0 = bm + 16 * MI * wm + 16 * mi + 4 * (l >> 4);
      #pragma unroll
      for (int j = 0; j < 4; j++) {
        if (OMODE == 0) {
          ((float*)C0 + (size_t)z*sC)[(size_t)(r0 + j) * ldc + c0] = acc[mi][ni][j];
        } else if (OMODE == 1) {
          ((ushort*)C0 + (size_t)z*sC)[(size_t)(r0 + j) * ldc + c0] = f2b(acc[mi][ni][j]);
        } else {
          if (c0 < 384)
            ((ushort*)C0 + (size_t)z*sC)[(size_t)(r0 + j) * 384 + c0] = f2b(acc[mi][ni][j]);
          else
            ((ushort*)C1 + (size_t)z*sC)[(size_t)(r0 + j) * 384 + (c0 - 384)] = f2b(acc[mi][ni][j]);
        }
      }
    }
  }
}

// ---------------- causal depthwise conv + silu: rolling window, CT rows/thread, z=4 ----------------
__global__ __launch_bounds__(256) void k_conv(const ushort* __restrict__ XC,
                                              const float* __restrict__ cw,
                                              const float* __restrict__ cb,
                                              ushort* __restrict__ U) {
  int z = blockIdx.y;
  int blk = z;
  int sgn = 1 - 2*(z >> 1);
  int i = blockIdx.x * 256 + threadIdx.x;     // over (LSEQ/CT)*(DI/8)
  if (i >= (LSEQ/CT) * (DI/8)) return;
  int tb = i / (DI/8), d0 = (i % (DI/8)) * 8;
  const ushort* X = XC + (size_t)z*LSEQ*DI;
  ushort* Uz = U + (size_t)z*LSEQ*DI;

  float wv[4][8];
  #pragma unroll
  for (int j = 0; j < 8; j++) {
    float4 t4 = *(const float4*)(cw + (size_t)blk*DI*DCONV + (d0+j)*DCONV);
    wv[0][j]=t4.x; wv[1][j]=t4.y; wv[2][j]=t4.z; wv[3][j]=t4.w;
  }
  float cbv[8];
  *(float4*)&cbv[0] = *(const float4*)(cb + blk*DI + d0);
  *(float4*)&cbv[4] = *(const float4*)(cb + blk*DI + d0 + 4);

  int tau0 = tb * CT;
  float win[3][8];
  #pragma unroll
  for (int q = 0; q < 3; q++) {
    int tau = tau0 - 3 + q;
    if (tau >= 0) {
      int r = (sgn > 0) ? tau : (LSEQ-1-tau);
      uint4 xv = *(const uint4*)(X + (size_t)r*DI + d0);
      const ushort* xs = (const ushort*)&xv;
      #pragma unroll
      for (int j = 0; j < 8; j++) win[q][j] = b2f(xs[j]);
    } else {
      #pragma unroll
      for (int j = 0; j < 8; j++) win[q][j] = 0.f;
    }
  }
  #pragma unroll
  for (int tt = 0; tt < CT; tt++) {
    int tau = tau0 + tt;
    int r = (sgn > 0) ? tau : (LSEQ-1-tau);
    float cur[8];
    uint4 xv = *(const uint4*)(X + (size_t)r*DI + d0);
    const ushort* xs = (const ushort*)&xv;
    #pragma unroll
    for (int j = 0; j < 8; j++) cur[j] = b2f(xs[j]);
    ushort outv[8];
    #pragma unroll
    for (int j = 0; j < 8; j++) {
      float a = cbv[j];
      a = fmaf(wv[0][j], win[0][j], a);
      a = fmaf(wv[1][j], win[1][j], a);
      a = fmaf(wv[2][j], win[2][j], a);
      a = fmaf(wv[3][j], cur[j],    a);
      outv[j] = f2b(siluf(a));
    }
    *(uint4*)(Uz + (size_t)r*DI + d0) = *(const uint4*)outv;
    #pragma unroll
    for (int j = 0; j < 8; j++) {
      win[0][j] = win[1][j]; win[1][j] = win[2][j]; win[2][j] = cur[j];
    }
  }
}

// ---------------- scan phase 1 (round-12 form, z=4): LDS Ps tile; local scan, yhat, chunk D/S ----------------
__global__ __launch_bounds__(128) void k_scan1(const ushort* __restrict__ UC,
                                               const float* __restrict__ PROJ,
                                               const float* __restrict__ Alog,
                                               const float* __restrict__ Wdt,
                                               const float* __restrict__ bdt,
                                               const float* __restrict__ Dp,
                                               float* __restrict__ Dc,
                                               ushort* __restrict__ Sc,
                                               ushort* __restrict__ Y) {
  __shared__ float Ps[TCH][NPROJ];
  int z = blockIdx.z;
  int blk = z;
  int sgn = 1 - 2*(z >> 1);
  const ushort* Uz = UC + (size_t)z*LSEQ*DI;
  const float* Pz = PROJ + (size_t)z*LSEQ*NPROJ;
  ushort* Yz = Y + (size_t)z*LSEQ*DI;
  int c = blockIdx.y;
  int dd = blockIdx.x * 128;
  int tid = threadIdx.x;
  int d = dd + tid;
  for (int j = tid; j < TCH * 11; j += 128) {
    int row = j / 11, q4 = j % 11;
    int s = c*TCH + row;
    int rg = (sgn > 0) ? s : (LSEQ-1-s);
    *(float4*)&Ps[row][q4*4] = *(const float4*)(Pz + (size_t)rg*NPROJ + q4*4);
  }
  __syncthreads();

  float wdt[DTRK];
  #pragma unroll
  for (int k = 0; k < DTRK; k++) wdt[k] = Wdt[(size_t)blk*DTRK*DI + k*DI + d];
  float bdtv = bdt[blk*DI + d];
  const float* Ablk = Alog + (size_t)blk*GDIM + (size_t)d*DSN;
  bool fast = true;
  #pragma unroll
  for (int n = 0; n < DSN; n++) {
    float An = -__expf(Ablk[n]);
    fast = fast && (fabsf(An + (float)(n+1)) <= 1e-3f * (n+1));
  }
  float dskip = Dp[blk*DI + d];
  float S[DSN] = {};
  float dtsum = 0.f;
  for (int t = 0; t < TCH; t++) {
    int s = c*TCH + t;
    int row = (sgn > 0) ? s : (LSEQ-1-s);
    float u = b2f(Uz[(size_t)row*DI + d]);
    const float* pr = &Ps[t][0];
    float dtp[12], Bv[DSN], Cv[DSN];
    *(float4*)&dtp[0] = *(const float4*)(pr + 0);
    *(float4*)&dtp[4] = *(const float4*)(pr + 4);
    *(float4*)&dtp[8] = *(const float4*)(pr + 8);
    *(float4*)&Bv[0]  = *(const float4*)(pr + 12);
    *(float4*)&Bv[4]  = *(const float4*)(pr + 16);
    *(float4*)&Bv[8]  = *(const float4*)(pr + 20);
    *(float4*)&Bv[12] = *(const float4*)(pr + 24);
    *(float4*)&Cv[0]  = *(const float4*)(pr + 28);
    *(float4*)&Cv[4]  = *(const float4*)(pr + 32);
    *(float4*)&Cv[8]  = *(const float4*)(pr + 36);
    *(float4*)&Cv[12] = *(const float4*)(pr + 40);
    float xdt = bdtv;
    #pragma unroll
    for (int k = 0; k < DTRK; k++) xdt = fmaf(dtp[k], wdt[k], xdt);
    float dtv = softplus_f(xdt);
    float du = dtv * u;
    dtsum += dtv;
    float a[DSN];
    if (fast) { pow16(__expf(-dtv), a); }
    else {
      #pragma unroll
      for (int n = 0; n < DSN; n++) a[n] = __expf(dtv * -__expf(Ablk[n]));
    }
    float y = u * dskip;
    #pragma unroll
    for (int n = 0; n < DSN; n++) {
      S[n] = a[n] * S[n] + du * Bv[n];
      y += S[n] * Cv[n];
    }
    Yz[(size_t)row * DI + d] = f2b(y);
  }
  Dc[(size_t)z*NCH*DI + (size_t)c*DI + d] = dtsum;
  ushort st[16];
  #pragma unroll
  for (int n = 0; n < DSN; n++) st[n] = f2b(S[n]);
  ushort* sp = Sc + (size_t)z*NCH*GDIM + (size_t)c*GDIM + (size_t)d*DSN;
  *(uint4*)sp       = *(const uint4*)&st[0];
  *(uint4*)(sp + 8) = *(const uint4*)&st[8];
}

// ---------------- scan 2a: compose 8-chunk groups (p regenerated from Dc), z=4 ----------------
__global__ __launch_bounds__(256) void k_scan2a(const float* __restrict__ Dc,
                                                const ushort* __restrict__ Sc,
                                                const float* __restrict__ Alog,
                                                float* __restrict__ PL,
                                                float* __restrict__ SL) {
  int g = blockIdx.x * 256 + threadIdx.x;
  int l = blockIdx.y;
  int z = blockIdx.z;
  int blk = z;
  int d = g >> 4;
  float A = -__expf(Alog[(size_t)blk*GDIM + g]);
  const float* Dz = Dc + (size_t)z*NCH*DI;
  const ushort* Sz = Sc + (size_t)z*NCH*GDIM;
  float Da = 0.f, Sa = 0.f;
  #pragma unroll
  for (int j = 0; j < RGRP; j++) {
    int c = l*RGRP + j;
    float D = Dz[(size_t)c*DI + d];
    float p = __expf(A * D);
    Sa = fmaf(p, Sa, b2f(Sz[(size_t)c*GDIM + g]));
    Da += D;
  }
  PL[(size_t)z*NGRP*GDIM + (size_t)l * GDIM + g] = __expf(A * Da);
  SL[(size_t)z*NGRP*GDIM + (size_t)l * GDIM + g] = Sa;
}

// ---------------- scan 2b: serial scan over 64 group summaries, z=4 ----------------
__global__ __launch_bounds__(256) void k_scan2b(const float* __restrict__ PL,
                                                const float* __restrict__ SL,
                                                float* __restrict__ HL) {
  int g = blockIdx.x * 256 + threadIdx.x;
  int z = blockIdx.y;
  const float* Pz = PL + (size_t)z*NGRP*GDIM;
  const float* Sz = SL + (size_t)z*NGRP*GDIM;
  float* Hz = HL + (size_t)z*NGRP*GDIM;
  float p[NGRP], s[NGRP];
  #pragma unroll
  for (int l = 0; l < NGRP; l++) {
    p[l] = Pz[(size_t)l * GDIM + g];
    s[l] = Sz[(size_t)l * GDIM + g];
  }
  float H = 0.f;
  #pragma unroll
  for (int l = 0; l < NGRP; l++) {
    Hz[(size_t)l * GDIM + g] = H;
    H = fmaf(p[l], H, s[l]);
  }
}

// ---------------- scan 2c: expand group states to per-chunk init states (Hc bf16), z=4 ----------------
__global__ __launch_bounds__(256) void k_scan2c(const float* __restrict__ Dc,
                                                const ushort* __restrict__ Sc,
                                                const float* __restrict__ HL,
                                                const float* __restrict__ Alog,
                                                ushort* __restrict__ Hc) {
  int g = blockIdx.x * 256 + threadIdx.x;
  int l = blockIdx.y;
  int z = blockIdx.z;
  int blk = z;
  int d = g >> 4;
  float A = -__expf(Alog[(size_t)blk*GDIM + g]);
  const float* Dz = Dc + (size_t)z*NCH*DI;
  const ushort* Sz = Sc + (size_t)z*NCH*GDIM;
  float h = HL[(size_t)z*NGRP*GDIM + (size_t)l * GDIM + g];
  ushort* Hz = Hc + (size_t)z*NCH*GDIM;
  #pragma unroll
  for (int j = 0; j < RGRP; j++) {
    int c = l*RGRP + j;
    size_t off = (size_t)c * GDIM + g;
    Hz[off] = f2b(h);
    float p = __expf(A * Dz[(size_t)c*DI + d]);
    h = fmaf(p, h, b2f(Sz[off]));
  }
}

// ---------------- fix (dt recomputed, round-9 form, z=4): y[t] += sum_n p[n]*Hinit[n]*C[t][n] ----------------
__global__ __launch_bounds__(128) void k_fix(const ushort* __restrict__ Hc,
                                             const float* __restrict__ PROJ,
                                             const float* __restrict__ Alog,
                                             const float* __restrict__ Wdt,
                                             const float* __restrict__ bdt,
                                             ushort* __restrict__ Y) {
  __shared__ float Dts[TCH][DTRK];
  __shared__ float Cs[TCH][DSN];
  int z = blockIdx.z;
  int c = blockIdx.y;
  int blk = z;
  int sgn = 1 - 2*(z >> 1);
  int dd = blockIdx.x * 128;
  int tid = threadIdx.x;
  int d = dd + tid;
  const float* Pz = PROJ + (size_t)z*LSEQ*NPROJ;
  ushort* Yz = Y + (size_t)z*LSEQ*DI;

  // stage dt cols (0..11) and C cols (28..43) for this chunk
  for (int j = tid; j < TCH * 3; j += 128) {
    int row = j / 3, q4 = j % 3;
    int s = c*TCH + row;
    int rg = (sgn > 0) ? s : (LSEQ-1-s);
    *(float4*)&Dts[row][q4*4] = *(const float4*)(Pz + (size_t)rg*NPROJ + q4*4);
  }
  {
    int row = tid >> 2, q4 = tid & 3;
    int s = c*TCH + row;
    int rg = (sgn > 0) ? s : (LSEQ-1-s);
    *(float4*)&Cs[row][q4*4] = *(const float4*)(Pz + (size_t)rg*NPROJ + 28 + q4*4);
  }

  float wdt[DTRK];
  #pragma unroll
  for (int k = 0; k < DTRK; k++) wdt[k] = Wdt[(size_t)blk*DTRK*DI + k*DI + d];
  float bdtv = bdt[blk*DI + d];
  const float* Ablk = Alog + (size_t)blk*GDIM + (size_t)d*DSN;
  bool fast = true;
  #pragma unroll
  for (int n = 0; n < DSN; n++) {
    float An = -__expf(Ablk[n]);
    fast = fast && (fabsf(An + (float)(n+1)) <= 1e-3f * (n+1));
  }
  float h[DSN];
  {
    const ushort* hp = Hc + (size_t)z*NCH*GDIM + (size_t)c*GDIM + (size_t)d*DSN;
    uint4 h0 = *(const uint4*)hp;
    uint4 h1 = *(const uint4*)(hp + 8);
    const ushort* hs0 = (const ushort*)&h0;
    const ushort* hs1 = (const ushort*)&h1;
    #pragma unroll
    for (int n = 0; n < 8; n++) { h[n] = b2f(hs0[n]); h[8+n] = b2f(hs1[n]); }
  }
  __syncthreads();

  float cd = 0.f;
  for (int t = 0; t < TCH; t++) {
    int s = c*TCH + t;
    int row = (sgn > 0) ? s : (LSEQ-1-s);
    float dtp[12], Cv[DSN];
    *(float4*)&dtp[0] = *(const float4*)&Dts[t][0];
    *(float4*)&dtp[4] = *(const float4*)&Dts[t][4];
    *(float4*)&dtp[8] = *(const float4*)&Dts[t][8];
    *(float4*)&Cv[0]  = *(const float4*)&Cs[t][0];
    *(float4*)&Cv[4]  = *(const float4*)&Cs[t][4];
    *(float4*)&Cv[8]  = *(const float4*)&Cs[t][8];
    *(float4*)&Cv[12] = *(const float4*)&Cs[t][12];
    float xdt = bdtv;
    #pragma unroll
    for (int k = 0; k < DTRK; k++) xdt = fmaf(dtp[k], wdt[k], xdt);
    cd += softplus_f(xdt);
    float p[DSN];
    if (fast) { pow16(__expf(-cd), p); }
    else {
      #pragma unroll
      for (int n = 0; n < DSN; n++) p[n] = __expf(cd * -__expf(Ablk[n]));
    }
    float corr = 0.f;
    #pragma unroll
    for (int n = 0; n < DSN; n++)
      corr = fmaf(p[n] * h[n], Cv[n], corr);
    size_t yi = (size_t)row*DI + d;
    Yz[yi] = f2b(b2f(Yz[yi]) + corr);
  }
}

// ---------------- final combine ----------------
__device__ __forceinline__ void ln_row(float (&v)[3], const float* __restrict__ w,
                                       const float* __restrict__ b, int lane) {
  float s = v[0] + v[1] + v[2];
  #pragma unroll
  for (int o = 32; o > 0; o >>= 1) s += __shfl_xor(s, o);
  float m = s * (1.f / DM);
  float q = 0.f;
  #pragma unroll
  for (int i = 0; i < 3; i++) { float d = v[i] - m; q += d*d; }
  #pragma unroll
  for (int o = 32; o > 0; o >>= 1) q += __shfl_xor(q, o);
  float inv = rsqrtf(q * (1.f / DM) + EPSV);
  #pragma unroll
  for (int i = 0; i < 3; i++) v[i] = (v[i] - m) * inv * w[lane + 64*i] + b[lane + 64*i];
}

// FIRST=1: out = x + cb (idx is a permutation). FIRST=0: out += cb.
template<int FIRST>
__global__ __launch_bounds__(64) void k_final(const float* __restrict__ x,
                                              const int* __restrict__ idx,
                                              const ushort* __restrict__ G4f,
                                              const ushort* __restrict__ G4b,
                                              const float* __restrict__ lnfw,
                                              const float* __restrict__ lnfb,
                                              const float* __restrict__ lnbw,
                                              const float* __restrict__ lnbb,
                                              const float* __restrict__ lnow,
                                              const float* __restrict__ lnob,
                                              float* __restrict__ out) {
  int t = blockIdx.x, lane = threadIdx.x;
  int r = idx[t];
  float f[3], g[3], cb[3];
  #pragma unroll
  for (int i = 0; i < 3; i++) {
    int j = lane + 64*i;
    float xo = x[(size_t)r*DM + j];
    f[i] = xo + b2f(G4f[(size_t)t*DM + j]);
    g[i] = xo + b2f(G4b[(size_t)t*DM + j]);
  }
  ln_row(f, lnfw, lnfb, lane);
  ln_row(g, lnbw, lnbb, lane);
  #pragma unroll
  for (int i = 0; i < 3; i++) cb[i] = f[i] + g[i];
  ln_row(cb, lnow, lnob, lane);
  #pragma unroll
  for (int i = 0; i < 3; i++) {
    int j = lane + 64*i;
    if (FIRST)
      out[(size_t)r*DM + j] = x[(size_t)r*DM + j] + cb[i];
    else
      out[(size_t)r*DM + j] += cb[i];
  }
}

extern "C" void kernel_launch(void* const* d_in, const int* in_sizes, int n_in,
                              void* d_out, int out_size, void* d_ws, size_t ws_size,
                              hipStream_t stream) {
  const float* x      = (const float*)d_in[0];
  const int*   orders = (const int*)  d_in[1];
  const float* nw     = (const float*)d_in[2];
  const float* Wi     = (const float*)d_in[3];
  const float* cw     = (const float*)d_in[4];
  const float* cbi    = (const float*)d_in[5];
  const float* Wx     = (const float*)d_in[6];
  const float* Wdt    = (const float*)d_in[7];
  const float* bdt    = (const float*)d_in[8];
  const float* Alog   = (const float*)d_in[9];
  const float* Dp     = (const float*)d_in[10];
  const float* Wo     = (const float*)d_in[11];
  const float* flw    = (const float*)d_in[12];
  const float* flb    = (const float*)d_in[13];
  const float* blw    = (const float*)d_in[14];
  const float* blb    = (const float*)d_in[15];
  const float* olw    = (const float*)d_in[16];
  const float* olb    = (const float*)d_in[17];
  float* outp = (float*)d_out;

  char* w = (char*)d_ws;
  size_t off = 0;
  auto take = [&](size_t bytes) -> void* {
    char* p = w + off;
    off += (bytes + 255) & ~(size_t)255;
    return (void*)p;
  };
  // z-slices: z = dir*2 + order, blk = z.
  ushort* Wct  = (ushort*)take((size_t)4 * 768 * DM * 2);
  ushort* Wxt  = (ushort*)take((size_t)4 * 64 * DI * 2);
  ushort* Wot  = (ushort*)take((size_t)4 * DM * DI * 2);
  ushort* xon  = (ushort*)take((size_t)2 * LSEQ * DM * 2);    // per order
  ushort* xc   = (ushort*)take((size_t)4 * LSEQ * DI * 2);    // per z; later aliased by ybuf
  ushort* zc   = (ushort*)take((size_t)4 * LSEQ * DI * 2);
  ushort* uc   = (ushort*)take((size_t)4 * LSEQ * DI * 2);    // conv out; later aliased by Hc
  float*  proj = (float*) take((size_t)4 * LSEQ * NPROJ * 4);
  ushort* g4   = (ushort*)take((size_t)4 * LSEQ * DM * 2);
  float*  Dc   = (float*) take((size_t)4 * NCH * DI * 4);
  ushort* Sc   = (ushort*)take((size_t)4 * NCH * GDIM * 2);
  float*  PL   = (float*) take((size_t)4 * NGRP * GDIM * 4);
  float*  SL   = (float*) take((size_t)4 * NGRP * GDIM * 4);
  float*  HL   = (float*) take((size_t)4 * NGRP * GDIM * 4);
  ushort* ybuf = xc;   // xc dead after conv; scan1 writes yhat here
  ushort* Hc   = uc;   // uc dead after scan1; 2c writes chunk-init states here
  (void)ws_size; (void)n_in; (void)in_sizes; (void)out_size;

  // weight prep, all 4 blocks, once
  k_prep<<<(PREP_A + PREP_B + PREP_C + 255)/256, 256, 0, stream>>>(
      Wi, nw, Wx, Wo, Wct, Wxt, Wot);
  // gather+rms for both orders
  k_gather_rms<<<dim3(LSEQ, 2), 64, 0, stream>>>(x, orders, xon);

  // in-proj (z=4): xc/zc = xon[z&1] @ Wc[z]
  k_mm<4,0,2><<<dim3(LSEQ/128, 768/64, 4), 256, 0, stream>>>(
      xon, nullptr, nullptr, Wct, xc, zc, 768, DM, DM, 0, 384, 1,
      (long)LSEQ*DM, 0L, 0L, (long)768*DM, (long)LSEQ*DI);
  // conv (z=4): uc = silu(conv(xc))
  k_conv<<<dim3(((LSEQ/CT)*(DI/8) + 255)/256, 4), 256, 0, stream>>>(
      xc, cw, cbi, uc);
  // x-proj (z=4): proj = uc @ Wx
  k_mm<2,0,0><<<dim3(LSEQ/64, 1, 4), 256, 0, stream>>>(
      uc, nullptr, nullptr, Wxt, proj, nullptr, NPROJ, DI, DI, 0, NPROJ, 3,
      (long)LSEQ*DI, 0L, 0L, (long)64*DI, (long)LSEQ*NPROJ);
  // scan1 (z=4): local scan + yhat + chunk D/S
  k_scan1<<<dim3(DI/128, NCH, 4), 128, 0, stream>>>(
      uc, proj, Alog, Wdt, bdt, Dp, Dc, Sc, ybuf);
  k_scan2a<<<dim3(GDIM/256, NGRP, 4), 256, 0, stream>>>(Dc, Sc, Alog, PL, SL);
  k_scan2b<<<dim3(GDIM/256, 4), 256, 0, stream>>>(PL, SL, HL);
  k_scan2c<<<dim3(GDIM/256, NGRP, 4), 256, 0, stream>>>(Dc, Sc, HL, Alog, Hc);
  // fix (z=4): in-place correction of ybuf (dt recomputed)
  k_fix<<<dim3(DI/128, NCH, 4), 128, 0, stream>>>(
      Hc, proj, Alog, Wdt, bdt, ybuf);
  // out-proj (z=4): g4 = (y * silu(z)) @ Wo
  k_mm<2,1,1><<<dim3(LSEQ/64, DM/64, 4), 256, 0, stream>>>(
      nullptr, ybuf, zc, Wot, g4, nullptr, DM, DI, DI, DI, DM, 3,
      0L, (long)LSEQ*DI, (long)LSEQ*DI, (long)DM*DI, (long)LSEQ*DM);

  // final: order 0 (z slices 0 fwd, 2 bwd) then order 1 (1 fwd, 3 bwd)
  k_final<1><<<LSEQ, 64, 0, stream>>>(x, orders, g4, g4 + (size_t)2*LSEQ*DM,
      flw, flb, blw, blb, olw, olb, outp);
  k_final<0><<<LSEQ, 64, 0, stream>>>(x, orders + LSEQ,
      g4 + (size_t)1*LSEQ*DM, g4 + (size_t)3*LSEQ*DM,
      flw + DM, flb + DM, blw + DM, blb + DM, olw + DM, olb + DM, outp);
}